// Round 2
// baseline (483.782 us; speedup 1.0000x reference)
//
#include <hip/hip_runtime.h>
#include <stdint.h>

// Problem constants
#define N_ 64
#define C_ 64
#define O_ 128
#define T_ 300
#define V_ 25
#define TB 4            // t-groups per block (divides 300)
#define KB 128          // GEMM K: k<64 raw x (residual), k>=64 xa (main)
#define LDB 136         // LDS B row stride in bf16 elements
#define LDX 136         // LDS Xs row stride in bf16 elements

typedef __attribute__((ext_vector_type(8))) short short8;
typedef __attribute__((ext_vector_type(4))) float floatx4;

__device__ __forceinline__ short f2bf(float f) {
  unsigned u = __float_as_uint(f);
  unsigned r = (u + 0x7FFFu + ((u >> 16) & 1u)) >> 16;
  return (short)(r & 0xFFFFu);
}

// ---------------- prep: fold BN into weights, M2 A-frags, bias table ----------
__global__ void sgc_prep(const float* __restrict__ A, const float* __restrict__ edge,
                         const float* __restrict__ gcn_w, const float* __restrict__ gcn_b,
                         const float* __restrict__ bn_g, const float* __restrict__ bn_b,
                         const float* __restrict__ bn_m, const float* __restrict__ bn_v,
                         const float* __restrict__ res_w, const float* __restrict__ res_b,
                         const float* __restrict__ rg, const float* __restrict__ rb,
                         const float* __restrict__ rm, const float* __restrict__ rv,
                         short* __restrict__ Wcat, short* __restrict__ M2A,
                         float* __restrict__ Cwp) {
  const int tid = threadIdx.x;
  // M2A: ready-to-use MFMA A-fragments of M2^T (A[m=w][k=v] = M2[v][w]).
  // idx = (mt2*64 + lane)*8 + i ; v = (lane>>4)*8 + i ; w = mt2*16 + (lane&15)
  for (int idx = tid; idx < 2 * 64 * 8; idx += 256) {
    const int i = idx & 7, lane = (idx >> 3) & 63, mt2 = idx >> 9;
    const int v = (lane >> 4) * 8 + i, w = mt2 * 16 + (lane & 15);
    M2A[idx] = (v < 25 && w < 25) ? f2bf(A[v * 25 + w] * edge[v * 25 + w]) : (short)0;
  }
  // Cw[o][w] = inv1*gcn_b*S[w] + (bn_b - bn_m*inv1) + inv2*res_b + (rb - rm*inv2)
  for (int i = tid; i < O_ * 32; i += 256) {
    const int o = i >> 5, w = i & 31;
    const float inv1 = bn_g[o] * rsqrtf(bn_v[o] + 1e-5f);
    const float inv2 = rg[o] * rsqrtf(rv[o] + 1e-5f);
    float S = 0.f;
    if (w < 25) {
      for (int v = 0; v < 25; ++v) S += A[v * 25 + w] * edge[v * 25 + w];
    }
    Cwp[i] = inv1 * gcn_b[o] * S + (bn_b[o] - bn_m[o] * inv1) + inv2 * res_b[o] +
             (rb[o] - rm[o] * inv2);
  }
  // Wcat bf16 [o][k]: k<64 -> inv2*res_w (raw x), k>=64 -> inv1*gcn_w (xa)
  for (int i = tid; i < O_ * KB; i += 256) {
    const int o = i >> 7, k = i & 127;
    const float inv1 = bn_g[o] * rsqrtf(bn_v[o] + 1e-5f);
    const float inv2 = rg[o] * rsqrtf(rv[o] + 1e-5f);
    const float val = (k < 64) ? inv2 * res_w[o * 64 + k] : inv1 * gcn_w[o * 64 + (k - 64)];
    Wcat[i] = f2bf(val);
  }
}

// ---------------- main fused kernel -------------------------------------------
// grid: 64 n * 75 t-blocks; block: 256 threads (4 waves)
__global__ __launch_bounds__(256, 3) void sgc_main(const float* __restrict__ x,
                                                   const short* __restrict__ Wcat,
                                                   const short* __restrict__ M2A,
                                                   const float* __restrict__ Cw,
                                                   float* __restrict__ out) {
  __shared__ short Bs[(TB * 32) * LDB];  // [j=(t,w or t,v)][k] 34816 B
  __shared__ short Xs[C_ * LDX];         // [c][j=(t,v)]        17408 B
  const int tid = threadIdx.x;
  const int b = blockIdx.x;
  const int n = b / 75;
  const int t0 = (b % 75) * TB;

  const int lane = tid & 63;
  const int wv = tid >> 6;
  const int l15 = lane & 15;
  const int quad = lane >> 4;
  const int obase = wv * 32;

  // Hoist all global weight-fragment loads to the top (overlap with phase 0).
  short8 af[2][4];  // main GEMM A-frags: A[m=o][k]
#pragma unroll
  for (int mt = 0; mt < 2; ++mt)
#pragma unroll
    for (int kq = 0; kq < 4; ++kq)
      af[mt][kq] = *(const short8*)(Wcat + (obase + mt * 16 + l15) * KB + kq * 32 + quad * 8);
  short8 am2[2];  // xa GEMM A-frags: A[m=w][k=v] = M2[v][w]
  am2[0] = *(const short8*)(M2A + lane * 8);
  am2[1] = *(const short8*)(M2A + (64 + lane) * 8);

  // ---- phase 0: coalesced float4 load of x block -> bf16 into Xs + Bs raw ----
  {
    const int c = tid >> 2, q = tid & 3;
    const floatx4* xp = (const floatx4*)(x + ((n * C_ + c) * T_ + t0) * V_);
#pragma unroll
    for (int i = 0; i < 7; ++i) {
      const int idx = q + 4 * i;  // float4 index within the 100-float run
      if (idx < 25) {
        const floatx4 f = xp[idx];
#pragma unroll
        for (int e = 0; e < 4; ++e) {
          const int flat = idx * 4 + e;     // 0..99 over (t-local, v)
          const int tl = flat / 25;
          const int v = flat - tl * 25;
          const short bv = f2bf(f[e]);
          const int j = tl * 32 + v;
          Xs[c * LDX + j] = bv;
          Bs[j * LDB + c] = bv;
        }
      }
    }
    // zero v-pad columns of Xs (K-dim pad for the xa GEMM); thread q zeros t=q
#pragma unroll
    for (int v = 25; v < 32; ++v) Xs[c * LDX + q * 32 + v] = 0;
  }
  __syncthreads();

  // ---- phase 1: xa = x @ M2 via MFMA (wave wv handles t-local = wv) ----------
  {
    floatx4 xacc[2][4];
#pragma unroll
    for (int mt2 = 0; mt2 < 2; ++mt2)
#pragma unroll
      for (int nt = 0; nt < 4; ++nt) xacc[mt2][nt] = (floatx4){0.f, 0.f, 0.f, 0.f};
#pragma unroll
    for (int nt = 0; nt < 4; ++nt) {
      const short8 bf = *(const short8*)(Xs + (nt * 16 + l15) * LDX + wv * 32 + quad * 8);
      xacc[0][nt] = __builtin_amdgcn_mfma_f32_16x16x32_bf16(am2[0], bf, xacc[0][nt], 0, 0, 0);
      xacc[1][nt] = __builtin_amdgcn_mfma_f32_16x16x32_bf16(am2[1], bf, xacc[1][nt], 0, 0, 0);
    }
    // D layout: col=l15 -> c-offset, row=quad*4+r -> w-offset
#pragma unroll
    for (int mt2 = 0; mt2 < 2; ++mt2)
#pragma unroll
      for (int nt = 0; nt < 4; ++nt) {
        const int c = nt * 16 + l15;
#pragma unroll
        for (int r = 0; r < 4; ++r) {
          const int w = mt2 * 16 + quad * 4 + r;
          if (w < 25) Bs[(wv * 32 + w) * LDB + 64 + c] = f2bf(xacc[mt2][nt][r]);
        }
      }
  }

  // ---- phase 2a: main GEMM, raw-x K-half (ready since sync1) -----------------
  floatx4 acc[2][8];
#pragma unroll
  for (int mt = 0; mt < 2; ++mt)
#pragma unroll
    for (int jt = 0; jt < 8; ++jt) acc[mt][jt] = (floatx4){0.f, 0.f, 0.f, 0.f};
#pragma unroll
  for (int jt = 0; jt < 8; ++jt) {
#pragma unroll
    for (int kq = 0; kq < 2; ++kq) {
      const short8 bf = *(const short8*)(&Bs[(jt * 16 + l15) * LDB + kq * 32 + quad * 8]);
      acc[0][jt] = __builtin_amdgcn_mfma_f32_16x16x32_bf16(af[0][kq], bf, acc[0][jt], 0, 0, 0);
      acc[1][jt] = __builtin_amdgcn_mfma_f32_16x16x32_bf16(af[1][kq], bf, acc[1][jt], 0, 0, 0);
    }
  }
  __syncthreads();

  // ---- phase 2b: main GEMM, xa K-half ----------------------------------------
#pragma unroll
  for (int jt = 0; jt < 8; ++jt) {
#pragma unroll
    for (int kq = 2; kq < 4; ++kq) {
      const short8 bf = *(const short8*)(&Bs[(jt * 16 + l15) * LDB + kq * 32 + quad * 8]);
      acc[0][jt] = __builtin_amdgcn_mfma_f32_16x16x32_bf16(af[0][kq], bf, acc[0][jt], 0, 0, 0);
      acc[1][jt] = __builtin_amdgcn_mfma_f32_16x16x32_bf16(af[1][kq], bf, acc[1][jt], 0, 0, 0);
    }
  }

  // ---- epilogue: + Cw, relu, store (C/D: col=l15 -> j, row=quad*4+r -> o) ----
#pragma unroll
  for (int mt = 0; mt < 2; ++mt) {
#pragma unroll
    for (int jt = 0; jt < 8; ++jt) {
      const int j = jt * 16 + l15;
      const int w = j & 31;
      if (w < 25) {
        const int tloc = j >> 5;
        const int o0 = obase + mt * 16 + quad * 4;
        float* op = out + (((n * O_ + o0) * T_) + (t0 + tloc)) * V_ + w;
        const float* cwp = Cw + o0 * 32 + w;
#pragma unroll
        for (int r = 0; r < 4; ++r) {
          const float val = acc[mt][jt][r] + cwp[r * 32];
          op[r * (T_ * V_)] = val > 0.f ? val : 0.f;
        }
      }
    }
  }
}

extern "C" void kernel_launch(void* const* d_in, const int* in_sizes, int n_in,
                              void* d_out, int out_size, void* d_ws, size_t ws_size,
                              hipStream_t stream) {
  const float* x = (const float*)d_in[0];
  const float* A = (const float*)d_in[1];
  const float* edge = (const float*)d_in[2];
  const float* gcn_w = (const float*)d_in[3];
  const float* gcn_b = (const float*)d_in[4];
  const float* bn_g = (const float*)d_in[5];
  const float* bn_b = (const float*)d_in[6];
  const float* bn_m = (const float*)d_in[7];
  const float* bn_v = (const float*)d_in[8];
  const float* res_w = (const float*)d_in[9];
  const float* res_b = (const float*)d_in[10];
  const float* rg = (const float*)d_in[11];
  const float* rb = (const float*)d_in[12];
  const float* rm = (const float*)d_in[13];
  const float* rv = (const float*)d_in[14];

  char* ws = (char*)d_ws;
  short* Wcat = (short*)(ws);           // 32768 B
  short* M2A = (short*)(ws + 32768);    // 2048 B
  float* Cwp = (float*)(ws + 34816);    // 16384 B
  float* out = (float*)d_out;

  hipLaunchKernelGGL(sgc_prep, dim3(1), dim3(256), 0, stream, A, edge, gcn_w, gcn_b,
                     bn_g, bn_b, bn_m, bn_v, res_w, res_b, rg, rb, rm, rv, Wcat, M2A, Cwp);
  hipLaunchKernelGGL(sgc_main, dim3(N_ * (T_ / TB)), dim3(256), 0, stream, x, Wcat, M2A,
                     Cwp, out);
}